// Round 12
// baseline (128.016 us; speedup 1.0000x reference)
//
#include <hip/hip_runtime.h>
#include <math.h>

#define NB   16      // batch
#define NTOK 4096    // N = 64*64
#define DIM  128
#define NE   8
#define HID  512
#define NOUT 128
#define GBLK 512     // gate blocks: each covers 128 contiguous tokens

// native 4-float vector for nontemporal builtins (HIP float4 is a class and
// is rejected by __builtin_nontemporal_*)
typedef float fvec4 __attribute__((ext_vector_type(4)));

static __device__ __forceinline__ float4 nt_load4(const float4* p) {
    fvec4 v = __builtin_nontemporal_load((const fvec4*)p);
    return make_float4(v.x, v.y, v.z, v.w);
}
static __device__ __forceinline__ void nt_store4(float4* p, float4 v) {
    fvec4 t;
    t.x = v.x; t.y = v.y; t.z = v.z; t.w = v.w;
    __builtin_nontemporal_store(t, (fvec4*)p);
}

// ws layout (all bytes read are written first each call):
//   s0      float[16*8]   @ 0    (512 B)
//   hitpart byte[512]     @ 512  (512 B)

// 8 lanes per token, grid-stride x4 tokens per lane, gate weights hoisted
// into VGPRs once per block. Nontemporal float4 x reads + zero-fill stores
// (read-once / write-once streams), 3-step butterfly, per-block hit bitmask,
// softmax score for expert 0 at n<8.
__global__ __launch_bounds__(256) void gate_kernel(
    const float4* __restrict__ x,        // (16,4096,128) f32 as float4
    const float* __restrict__ wg,        // (128,8)
    const float* __restrict__ bg,        // (8)
    float* __restrict__ s0,              // ws (16,8)
    unsigned char* __restrict__ hitpart, // ws (512) one byte per block
    float4* __restrict__ out)            // (16,4096,128) f32
{
    __shared__ float4 lw4[NE][DIM / 4];  // wg transposed
    __shared__ float lbg[NE];
    __shared__ unsigned int lmask;

    int tid = threadIdx.x;
    {   // stage wg transposed (one float4 per thread)
        int e = tid >> 5, s = tid & 31, d0 = s * 4;
        float4 w;
        w.x = wg[(d0 + 0) * NE + e];
        w.y = wg[(d0 + 1) * NE + e];
        w.z = wg[(d0 + 2) * NE + e];
        w.w = wg[(d0 + 3) * NE + e];
        lw4[e][s] = w;
    }
    if (tid < NE) lbg[tid] = bg[tid];
    if (tid == 0) lmask = 0u;
    __syncthreads();

    int sub  = tid & 7;       // lane-within-token
    int tgrp = tid >> 3;      // token-within-chunk (0..31)

    // hoist this lane's weight slice into VGPRs (reused for all 4 groups)
    float4 wv[NE][4];
    #pragma unroll
    for (int e = 0; e < NE; e++)
        #pragma unroll
        for (int k = 0; k < 4; k++) wv[e][k] = lw4[e][sub + 8 * k];

    #pragma unroll 2
    for (int it = 0; it < 4; it++) {
        int tok = (blockIdx.x << 7) + (it << 5) + tgrp;   // 0..65535
        int b   = tok >> 12;
        int n   = tok & 4095;
        size_t base = (size_t)tok * 32 + sub;

        // nontemporal zero-fill first (independent stores overlap latency)
        float4 zz = make_float4(0.f, 0.f, 0.f, 0.f);
        nt_store4(&out[base], zz);
        nt_store4(&out[base + 8], zz);
        nt_store4(&out[base + 16], zz);
        nt_store4(&out[base + 24], zz);

        // read-once x stream, nontemporal
        float4 xv0 = nt_load4(&x[base]);
        float4 xv1 = nt_load4(&x[base + 8]);
        float4 xv2 = nt_load4(&x[base + 16]);
        float4 xv3 = nt_load4(&x[base + 24]);

        float z[NE];
        #pragma unroll
        for (int e = 0; e < NE; e++) {
            z[e] = xv0.x * wv[e][0].x + xv0.y * wv[e][0].y
                 + xv0.z * wv[e][0].z + xv0.w * wv[e][0].w
                 + xv1.x * wv[e][1].x + xv1.y * wv[e][1].y
                 + xv1.z * wv[e][1].z + xv1.w * wv[e][1].w
                 + xv2.x * wv[e][2].x + xv2.y * wv[e][2].y
                 + xv2.z * wv[e][2].z + xv2.w * wv[e][2].w
                 + xv3.x * wv[e][3].x + xv3.y * wv[e][3].y
                 + xv3.z * wv[e][3].z + xv3.w * wv[e][3].w;
        }

        // butterfly sum across the 8 lanes of this token (xor 1,2,4)
        #pragma unroll
        for (int off = 1; off <= 4; off <<= 1) {
            #pragma unroll
            for (int e = 0; e < NE; e++) z[e] += __shfl_xor(z[e], off);
        }

        if (sub == 0) {
            float zf[NE];
            #pragma unroll
            for (int e = 0; e < NE; e++) zf[e] = z[e] + lbg[e];

            int am = 0;
            float mz = zf[0];
            #pragma unroll
            for (int e = 1; e < NE; e++) {
                if (zf[e] > mz) { mz = zf[e]; am = e; }
            }
            atomicOr(&lmask, 1u << am);   // LDS atomic

            if (n < 8) {                   // softmax score for expert 0
                float s = 0.f;
                #pragma unroll
                for (int e = 0; e < NE; e++) s += expf(zf[e] - mz);
                s0[b * NE + n] = expf(zf[0] - mz) / s;
            }
        }
    }

    __syncthreads();
    if (tid == 0) hitpart[blockIdx.x] = (unsigned char)lmask;
}

// Fused expert-0 MixFFN + gate scale for the 128 nonzero output rows.
// grid = 16 batches x 8 token positions (w), 256 threads.
// All hot loads are vector loads with deep batching; x rows staged in LDS.
// fc1 K-split-2: thread (q = tid&127, kh = tid>>7) owns channels 4q..4q+3
// over d-range [kh*64, kh*64+64); partials reduced via LDS; dwconv in
// registers; fc2 with 32-wide W2 load batches.
__global__ __launch_bounds__(256) void expert_kernel(
    const float* __restrict__ x,
    const float* __restrict__ W1,   // (8,128,512) -> expert 0 slice
    const float* __restrict__ B1,   // (8,512)
    const float* __restrict__ Wd,   // (8,3,3,1,512)
    const float* __restrict__ Bd,   // (8,512)
    const float* __restrict__ W2,   // (8,512,128) -> expert 0 slice
    const float* __restrict__ B2,   // (8,128)
    const float* __restrict__ s0,
    const unsigned char* __restrict__ hitpart,
    float* __restrict__ out)
{
    __shared__ float4 xs4[6][32];     //  3 KB: xs[p][d], p = row*3 + ci
    __shared__ float4 redb[128][6];   // 12 KB: k-half-1 fc1 partials
    __shared__ float gls[HID];        //  2 KB
    __shared__ float red2[256];
    __shared__ unsigned int hm[NB];
    __shared__ float gate_s;

    int b = blockIdx.x >> 3;
    int w = blockIdx.x & 7;      // token position = gate index
    int tid = threadIdx.x;

    // hit bitmask (512 B = 32 uint4): 2 uint4 per batch, no atomics
    if (tid < NB) {
        const uint4* hp = (const uint4*)hitpart;
        uint4 v0 = hp[tid * 2], v1 = hp[tid * 2 + 1];
        unsigned int m = v0.x | v0.y | v0.z | v0.w | v1.x | v1.y | v1.z | v1.w;
        m |= m >> 16; m |= m >> 8; m &= 0xffu;
        hm[tid] = m;
    }

    // stage x rows (row 0..1) x (cols w-1..w+1): 192 float4, coalesced.
    // col<0 clamps to 0 (garbage values; dwconv skips that tap).
    if (tid < 192) {
        int p = tid >> 5, dq = tid & 31;
        int row = p / 3, ci = p % 3;
        int col = w - 1 + ci;
        if (col < 0) col = 0;
        xs4[p][dq] = ((const float4*)x)[((size_t)b * NTOK + row * 64 + col) * 32 + dq];
    }
    __syncthreads();

    if (tid == 0) {
        float denom = 1e-6f, mine = 0.f;
        for (int bb = 0; bb < NB; bb++) {
            float v = ((hm[bb] >> w) & 1u) ? s0[bb * NE + w] : 0.f;
            denom += v;
            if (bb == b) mine = v;
        }
        gate_s = 16.0f * mine / denom;
    }

    // fc1: acc[p][j] = sum_d xs[p][d] * W1[d][4q+j], K-split over kh
    int q  = tid & 127;       // float4-column: channels 4q..4q+3
    int kh = tid >> 7;        // 0/1: d in [kh*64, kh*64+64)
    float4 acc[6];
    #pragma unroll
    for (int p = 0; p < 6; p++) acc[p] = make_float4(0.f, 0.f, 0.f, 0.f);

    const float4* W14 = (const float4*)W1;   // [128][128] float4 view
    #pragma unroll 4
    for (int s = 0; s < 16; s++) {
        int d0 = kh * 64 + s * 4;
        float4 wv0 = W14[(size_t)(d0 + 0) * 128 + q];
        float4 wv1 = W14[(size_t)(d0 + 1) * 128 + q];
        float4 wv2 = W14[(size_t)(d0 + 2) * 128 + q];
        float4 wv3 = W14[(size_t)(d0 + 3) * 128 + q];
        #pragma unroll
        for (int p = 0; p < 6; p++) {
            float4 xv = xs4[p][kh * 16 + s];
            acc[p].x += xv.x * wv0.x + xv.y * wv1.x + xv.z * wv2.x + xv.w * wv3.x;
            acc[p].y += xv.x * wv0.y + xv.y * wv1.y + xv.z * wv2.y + xv.w * wv3.y;
            acc[p].z += xv.x * wv0.z + xv.y * wv1.z + xv.z * wv2.z + xv.w * wv3.z;
            acc[p].w += xv.x * wv0.w + xv.y * wv1.w + xv.z * wv2.w + xv.w * wv3.w;
        }
    }

    // reduce the two k-halves via LDS
    if (kh == 1) {
        #pragma unroll
        for (int p = 0; p < 6; p++) redb[q][p] = acc[p];
    }
    __syncthreads();

    // dwconv + biases + exact gelu on the low-half threads (4 channels each)
    if (kh == 0) {
        #pragma unroll
        for (int p = 0; p < 6; p++) {
            float4 r = redb[q][p];
            acc[p].x += r.x; acc[p].y += r.y; acc[p].z += r.z; acc[p].w += r.w;
        }
        float4 b1 = ((const float4*)B1)[q];
        float4 y  = ((const float4*)Bd)[q];
        #pragma unroll
        for (int ci = 0; ci < 3; ci++) {
            int col = w - 1 + ci;
            if (col < 0) continue;   // SAME-padding: h1 entry is 0, skip tap
            float4 wda = ((const float4*)Wd)[(3 + ci) * 128 + q];  // kh=1 -> row 0
            float4 wdb = ((const float4*)Wd)[(6 + ci) * 128 + q];  // kh=2 -> row 1
            float4 a0 = acc[ci];       // row 0, this col
            float4 a1 = acc[3 + ci];   // row 1, this col
            y.x += (a0.x + b1.x) * wda.x + (a1.x + b1.x) * wdb.x;
            y.y += (a0.y + b1.y) * wda.y + (a1.y + b1.y) * wdb.y;
            y.z += (a0.z + b1.z) * wda.z + (a1.z + b1.z) * wdb.z;
            y.w += (a0.w + b1.w) * wda.w + (a1.w + b1.w) * wdb.w;
        }
        const float k = 0.70710678118654752f;
        float4 g;
        g.x = 0.5f * y.x * (1.0f + erff(y.x * k));
        g.y = 0.5f * y.y * (1.0f + erff(y.y * k));
        g.z = 0.5f * y.z * (1.0f + erff(y.z * k));
        g.w = 0.5f * y.w * (1.0f + erff(y.w * k));
        ((float4*)gls)[q] = g;
    }
    __syncthreads();

    // fc2: 2-way c-split, lane = output channel, 32 W2 loads in flight
    int o    = tid & 127;
    int half = tid >> 7;
    const float* wp = W2 + (size_t)(half * 256) * NOUT + o;
    const float4* gp = (const float4*)&gls[half * 256];
    float a = 0.f;
    #pragma unroll
    for (int cb = 0; cb < 256; cb += 32) {
        float wvv[32];
        #pragma unroll
        for (int k2 = 0; k2 < 32; k2++) wvv[k2] = wp[(size_t)(cb + k2) * NOUT];
        #pragma unroll
        for (int k2 = 0; k2 < 32; k2 += 4) {
            float4 g = gp[(cb + k2) >> 2];
            a += g.x * wvv[k2] + g.y * wvv[k2 + 1] + g.z * wvv[k2 + 2] + g.w * wvv[k2 + 3];
        }
    }
    red2[tid] = a;
    __syncthreads();
    if (tid < 128) {
        out[((size_t)b * NTOK + w) * NOUT + o] =
            (red2[tid] + red2[tid + 128] + B2[o]) * gate_s;
    }
}

extern "C" void kernel_launch(void* const* d_in, const int* in_sizes, int n_in,
                              void* d_out, int out_size, void* d_ws, size_t ws_size,
                              hipStream_t stream) {
    const float* x  = (const float*)d_in[0];
    // d_in[1] = H, d_in[2] = W (ints) — fixed 64x64, hard-coded
    const float* wg = (const float*)d_in[3];
    const float* bg = (const float*)d_in[4];
    const float* W1 = (const float*)d_in[5];
    const float* B1 = (const float*)d_in[6];
    const float* Wd = (const float*)d_in[7];
    const float* Bd = (const float*)d_in[8];
    const float* W2 = (const float*)d_in[9];
    const float* B2 = (const float*)d_in[10];

    float* s0              = (float*)d_ws;
    unsigned char* hitpart = (unsigned char*)d_ws + 512;

    gate_kernel<<<GBLK, 256, 0, stream>>>(
        (const float4*)x, wg, bg, s0, hitpart, (float4*)d_out);
    expert_kernel<<<NB * NE, 256, 0, stream>>>(
        x, W1, B1, Wd, Bd, W2, B2, s0, hitpart, (float*)d_out);
}